// Round 2
// baseline (391.494 us; speedup 1.0000x reference)
//
#include <hip/hip_runtime.h>
#include <hip/hip_bf16.h>

#define N_ATOMS 10000
#define N_PAIR  100000
#define F_DIM   128
#define N_HEAD  4
#define FH      32
#define N_DEG   3
#define M_TOT   15
#define K_RBF   32

typedef __attribute__((ext_vector_type(8))) short short8;   // 8 bf16 = 4 VGPRs
typedef __attribute__((ext_vector_type(4))) float f32x4;

union frag_cast { int i[4]; short8 s; };

__device__ __forceinline__ float sspf(float v) {
    float sp = fmaxf(v, 0.f) + log1pf(expf(-fabsf(v)));
    return sp - 0.69314718055994531f;
}

__device__ __forceinline__ unsigned short bf16_rne(float x) {
    unsigned int u = __float_as_uint(x);
    unsigned int r = u + 0x7fffu + ((u >> 16) & 1u);
    return (unsigned short)(r >> 16);
}
__device__ __forceinline__ float bf16_tof(unsigned short h) {
    return __uint_as_float(((unsigned int)h) << 16);
}

// ---------------- Generic 128-col GEMM (fp32, used for x@W_in only) ---------
__global__ __launch_bounds__(256) void k_gemm128(
    const float* __restrict__ A, const float* __restrict__ B,
    const float* __restrict__ bias, float* __restrict__ C, int rows)
{
    __shared__ float As[32][132];
    __shared__ float Bs[32][132];
    int r0 = blockIdx.x * 128;
    int t = threadIdx.x;
    int ty = t >> 4, tx = t & 15;

    float acc[8][8];
    #pragma unroll
    for (int i = 0; i < 8; ++i)
        #pragma unroll
        for (int j = 0; j < 8; ++j) acc[i][j] = 0.f;

    for (int k0 = 0; k0 < 128; k0 += 32) {
        #pragma unroll
        for (int r = 0; r < 16; ++r) {
            int idx = t + 256 * r;
            int row = idx >> 5, kk = idx & 31;
            int grow = r0 + row;
            As[kk][row] = (grow < rows) ? A[grow * 128 + k0 + kk] : 0.f;
        }
        #pragma unroll
        for (int r = 0; r < 16; ++r) {
            int idx = t + 256 * r;
            int kk = idx >> 7, c = idx & 127;
            Bs[kk][c] = B[(k0 + kk) * 128 + c];
        }
        __syncthreads();

        #pragma unroll
        for (int kk = 0; kk < 32; ++kk) {
            float a[8], b[8];
            *(float4*)&a[0] = *(const float4*)&As[kk][ty * 4];
            *(float4*)&a[4] = *(const float4*)&As[kk][64 + ty * 4];
            *(float4*)&b[0] = *(const float4*)&Bs[kk][tx * 4];
            *(float4*)&b[4] = *(const float4*)&Bs[kk][64 + tx * 4];
            #pragma unroll
            for (int i = 0; i < 8; ++i)
                #pragma unroll
                for (int j = 0; j < 8; ++j)
                    acc[i][j] = fmaf(a[i], b[j], acc[i][j]);
        }
        __syncthreads();
    }

    float bj[8];
    #pragma unroll
    for (int j = 0; j < 4; ++j) { bj[j] = bias[tx * 4 + j]; bj[4 + j] = bias[64 + tx * 4 + j]; }

    #pragma unroll
    for (int i = 0; i < 8; ++i) {
        int row = r0 + ((i < 4) ? (ty * 4 + i) : (64 + ty * 4 + (i - 4)));
        if (row < rows) {
            float4 v0, v1;
            v0.x = acc[i][0] + bj[0]; v0.y = acc[i][1] + bj[1];
            v0.z = acc[i][2] + bj[2]; v0.w = acc[i][3] + bj[3];
            v1.x = acc[i][4] + bj[4]; v1.y = acc[i][5] + bj[5];
            v1.z = acc[i][6] + bj[6]; v1.w = acc[i][7] + bj[7];
            *(float4*)&C[row * 128 + tx * 4] = v0;
            *(float4*)&C[row * 128 + 64 + tx * 4] = v1;
        }
    }
}

// ---------------- Q/K projection: 32 atoms/block (313 blocks) ---------------
__global__ __launch_bounds__(384) void k_qk(
    const float* __restrict__ xh, const float* __restrict__ W_Q,
    const float* __restrict__ W_K, float* __restrict__ Q, float* __restrict__ K)
{
    __shared__ float xfs[32][128];
    int t = threadIdx.x;                 // == e
    int h = (t >> 5) & 3;
    float wq[32], wk[32];
    const float4* wqp = (const float4*)(W_Q + t * 32);
    const float4* wkp = (const float4*)(W_K + t * 32);
    #pragma unroll
    for (int j4 = 0; j4 < 8; ++j4) {
        float4 a = wqp[j4], b = wkp[j4];
        wq[4 * j4 + 0] = a.x; wq[4 * j4 + 1] = a.y; wq[4 * j4 + 2] = a.z; wq[4 * j4 + 3] = a.w;
        wk[4 * j4 + 0] = b.x; wk[4 * j4 + 1] = b.y; wk[4 * j4 + 2] = b.z; wk[4 * j4 + 3] = b.w;
    }
    int ab = blockIdx.x * 32;
    for (int idx = t; idx < 4096; idx += 384) {
        int aa = idx >> 7, f = idx & 127;
        int ag = ab + aa;
        xfs[aa][f] = (ag < N_ATOMS) ? xh[ag * 128 + f] : 0.f;
    }
    __syncthreads();
    for (int aa = 0; aa < 32; ++aa) {
        int ag = ab + aa;
        if (ag >= N_ATOMS) break;
        const float4* xv = (const float4*)&xfs[aa][h * 32];
        float q0 = 0.f, q1 = 0.f, k0 = 0.f, k1 = 0.f;
        #pragma unroll
        for (int j4 = 0; j4 < 8; j4 += 2) {
            float4 x0 = xv[j4], x1 = xv[j4 + 1];
            q0 = fmaf(wq[4 * j4 + 0], x0.x, q0); q0 = fmaf(wq[4 * j4 + 1], x0.y, q0);
            q0 = fmaf(wq[4 * j4 + 2], x0.z, q0); q0 = fmaf(wq[4 * j4 + 3], x0.w, q0);
            q1 = fmaf(wq[4 * j4 + 4], x1.x, q1); q1 = fmaf(wq[4 * j4 + 5], x1.y, q1);
            q1 = fmaf(wq[4 * j4 + 6], x1.z, q1); q1 = fmaf(wq[4 * j4 + 7], x1.w, q1);
            k0 = fmaf(wk[4 * j4 + 0], x0.x, k0); k0 = fmaf(wk[4 * j4 + 1], x0.y, k0);
            k0 = fmaf(wk[4 * j4 + 2], x0.z, k0); k0 = fmaf(wk[4 * j4 + 3], x0.w, k0);
            k1 = fmaf(wk[4 * j4 + 4], x1.x, k1); k1 = fmaf(wk[4 * j4 + 5], x1.y, k1);
            k1 = fmaf(wk[4 * j4 + 6], x1.z, k1); k1 = fmaf(wk[4 * j4 + 7], x1.w, k1);
        }
        Q[ag * 384 + t] = q0 + q1;
        K[ag * 384 + t] = k0 + k1;
    }
}

// ---------------- W_f2 -> transposed hi/lo bf16  [e][k] ---------------------
__global__ __launch_bounds__(256) void k_cvt_w2(
    const float* __restrict__ W, unsigned short* __restrict__ Wh,
    unsigned short* __restrict__ Wl)
{
    int idx = blockIdx.x * 256 + threadIdx.x;   // 12288 total
    if (idx < 12288) {
        int e = idx >> 5, k = idx & 31;
        float v = W[k * 384 + e];               // W_f2 is [32][384]
        unsigned short h = bf16_rne(v);
        unsigned short l = bf16_rne(v - bf16_tof(h));
        Wh[e * 32 + k] = h;
        Wl[e * 32 + k] = l;
    }
}

// ---------------- Pair kernel: MFMA for h1 @ W_f2 ---------------------------
// 16 pairs/block, 256 threads (4 waves), grid 6250. LDS ~27.5 KB -> 5
// blocks/CU (20 waves). g_s padded to 388 floats/row: row-stride = 16 mod 32
// banks -> quad reads are 2-way conflicted (free). bf16 hi/lo MFMA keeps
// fp32-class precision.
__global__ __launch_bounds__(256) void k_pair(
    const float* __restrict__ rbf, const float* __restrict__ phi,
    const float* __restrict__ mask, const int* __restrict__ idx_i,
    const int* __restrict__ idx_j, const float* __restrict__ W_f1,
    const float* __restrict__ b_f1, const unsigned short* __restrict__ W2h,
    const unsigned short* __restrict__ W2l, const float* __restrict__ b_f2,
    const float* __restrict__ Q, const float* __restrict__ K,
    float* __restrict__ alpha)
{
    __shared__ float g_s[16][388];            // 24.8 KB; also staging for rbf/W_f1
    __shared__ unsigned int h1p_s[16][36];    // packed (hi<<16)|lo bf16, padded
    __shared__ int   i_s[16];
    __shared__ int   j_s[16];
    __shared__ float phim_s[16];              // phi * m^2 * 1/sqrt(32)

    float (*rbf_s)[33] = (float (*)[33])(&g_s[0][0]);           // 16 rows
    float (*wf1_s)[33] = (float (*)[33])(&g_s[0][0] + 16 * 33); // 32 rows

    int t = threadIdx.x;
    int p0 = blockIdx.x * 16;                 // N_PAIR = 6250*16 exactly

    // stage rbf (16x32) and W_f1 (32x32) into the (to-be-overwritten) g region
    for (int idx = t; idx < 1536; idx += 256) {
        if (idx < 512) {
            rbf_s[idx >> 5][idx & 31] = rbf[p0 * 32 + idx];
        } else {
            int k = idx - 512;
            wf1_s[k >> 5][k & 31] = W_f1[k];
        }
    }
    if (t < 16) {
        int pg = p0 + t;
        i_s[t] = idx_i[pg];
        j_s[t] = idx_j[pg];
        float m = mask[pg];
        phim_s[t] = phi[pg] * m * m * 0.17677669529663687f;
    }
    __syncthreads();

    // h1 = ssp(rbf @ W_f1 + b1), split to bf16 hi/lo, pack into LDS
    {
        int p = t >> 4, c0 = (t & 15) * 2;
        float acc0 = b_f1[c0], acc1 = b_f1[c0 + 1];
        #pragma unroll
        for (int k = 0; k < 32; ++k) {
            float rv = rbf_s[p][k];
            acc0 = fmaf(rv, wf1_s[k][c0], acc0);
            acc1 = fmaf(rv, wf1_s[k][c0 + 1], acc1);
        }
        float h0 = sspf(acc0), h1v = sspf(acc1);
        unsigned short hh0 = bf16_rne(h0);
        unsigned short ll0 = bf16_rne(h0 - bf16_tof(hh0));
        unsigned short hh1 = bf16_rne(h1v);
        unsigned short ll1 = bf16_rne(h1v - bf16_tof(hh1));
        h1p_s[p][c0]     = ((unsigned int)hh0 << 16) | (unsigned int)ll0;
        h1p_s[p][c0 + 1] = ((unsigned int)hh1 << 16) | (unsigned int)ll1;
    }
    __syncthreads();   // h1 done; now safe to overwrite rbf/W_f1 staging with g

    // g[p][e] = Q[i_p*384+e] * K[j_p*384+e] via coalesced float4 loads
    #pragma unroll
    for (int it = 0; it < 6; ++it) {
        int idx = it * 256 + t;               // 0..1535 = 16 pairs x 96 float4
        int p = idx / 96;
        int c4 = idx - p * 96;
        const float4* qp = (const float4*)(Q + i_s[p] * 384) + c4;
        const float4* kp = (const float4*)(K + j_s[p] * 384) + c4;
        float4 qv = *qp, kv = *kp;
        float4 gv;
        gv.x = qv.x * kv.x; gv.y = qv.y * kv.y;
        gv.z = qv.z * kv.z; gv.w = qv.w * kv.w;
        *(float4*)&g_s[p][c4 * 4] = gv;
    }
    __syncthreads();

    // MFMA phase: S = h1 @ W_f2 (K=32 = one mfma k-step), then
    // alpha[p][dh] = phim * sum_e (S[p][e] + b2[e]) * g[p][e]
    int wave = t >> 6, lane = t & 63;
    int quad = lane >> 4, l15 = lane & 15;

    // A fragments (single 16-row tile), hi and lo
    short8 ah, al;
    {
        const unsigned int* hp = &h1p_s[l15][quad * 8];
        uint4 u01 = *(const uint4*)hp;
        uint4 u23 = *(const uint4*)(hp + 4);
        unsigned int u[8] = {u01.x, u01.y, u01.z, u01.w, u23.x, u23.y, u23.z, u23.w};
        frag_cast fh, fl;
        #pragma unroll
        for (int q = 0; q < 4; ++q) {
            unsigned int a0 = u[2 * q], a1 = u[2 * q + 1];
            fh.i[q] = (int)((a0 >> 16) | (a1 & 0xffff0000u));
            fl.i[q] = (int)((a0 & 0xffffu) | (a1 << 16));
        }
        ah = fh.s;
        al = fl.s;
    }

    #pragma unroll
    for (int dd = 0; dd < 3; ++dd) {
        int dh = wave * 3 + dd;
        int e_base = dh * 32;
        // B fragments for the dh group's two 16-col tiles
        short8 bh0 = *(const short8*)(W2h + (e_base + l15) * 32 + quad * 8);
        short8 bl0 = *(const short8*)(W2l + (e_base + l15) * 32 + quad * 8);
        short8 bh1 = *(const short8*)(W2h + (e_base + 16 + l15) * 32 + quad * 8);
        short8 bl1 = *(const short8*)(W2l + (e_base + 16 + l15) * 32 + quad * 8);
        float b2v0 = b_f2[e_base + l15];
        float b2v1 = b_f2[e_base + 16 + l15];

        f32x4 s0 = {0.f, 0.f, 0.f, 0.f};
        f32x4 s1 = {0.f, 0.f, 0.f, 0.f};
        s0 = __builtin_amdgcn_mfma_f32_16x16x32_bf16(ah, bh0, s0, 0, 0, 0);
        s1 = __builtin_amdgcn_mfma_f32_16x16x32_bf16(ah, bh1, s1, 0, 0, 0);
        s0 = __builtin_amdgcn_mfma_f32_16x16x32_bf16(al, bh0, s0, 0, 0, 0);
        s1 = __builtin_amdgcn_mfma_f32_16x16x32_bf16(al, bh1, s1, 0, 0, 0);
        s0 = __builtin_amdgcn_mfma_f32_16x16x32_bf16(ah, bl0, s0, 0, 0, 0);
        s1 = __builtin_amdgcn_mfma_f32_16x16x32_bf16(ah, bl1, s1, 0, 0, 0);

        float vsum[4];
        #pragma unroll
        for (int r = 0; r < 4; ++r) {
            int prow = quad * 4 + r;
            float v = (s0[r] + b2v0) * g_s[prow][e_base + l15]
                    + (s1[r] + b2v1) * g_s[prow][e_base + 16 + l15];
            #pragma unroll
            for (int off = 8; off >= 1; off >>= 1)
                v += __shfl_xor(v, off, 16);
            vsum[r] = v;
        }
        if (l15 == 0) {
            #pragma unroll
            for (int r = 0; r < 4; ++r) {
                int prow = quad * 4 + r;
                alpha[(p0 + prow) * 12 + dh] = vsum[r] * phim_s[prow];
            }
        }
    }
}

__device__ __forceinline__ int lower_bound_i(const int* __restrict__ arr, int n, int val) {
    int lo = 0, hi = n;
    while (lo < hi) {
        int mid = (lo + hi) >> 1;
        if (arr[mid] < val) lo = mid + 1; else hi = mid;
    }
    return lo;
}

__global__ __launch_bounds__(256) void k_seg(const int* __restrict__ idx_i,
                                             int* __restrict__ seg)
{
    int a = blockIdx.x * 256 + threadIdx.x;
    if (a <= N_ATOMS) seg[a] = lower_bound_i(idx_i, N_PAIR, a);
}

// ---------------- W_out -> transposed hi/lo bf16 ----------------------------
__global__ __launch_bounds__(256) void k_cvt_b(
    const float* __restrict__ W, unsigned short* __restrict__ Bth,
    unsigned short* __restrict__ Btl)
{
    int idx = blockIdx.x * 256 + threadIdx.x;   // 16384 total
    int cc = idx >> 7, kk = idx & 127;
    float v = W[kk * 128 + cc];                 // transpose read
    unsigned short h = bf16_rne(v);
    unsigned short l = bf16_rne(v - bf16_tof(h));
    Bth[cc * 128 + kk] = h;
    Btl[cc * 128 + kk] = l;
}

// ---------------- Fused segment aggregation + out GEMM ----------------------
// 2 atoms/block, 512 threads. Phase 1: per-atom segment reduction (identical
// structure to the old k_agg), agg packed hi/lo bf16 into LDS (row-stride 132
// uints -> A-frag reads spread across bank groups). Phase 2: 16x128x128
// bf16x3 MFMA per atom straight from LDS; eliminates the 77 MB agg global
// round-trip and the separate k_out kernel.
__global__ __launch_bounds__(512) void k_agg_out(
    const float* __restrict__ xh, const float* __restrict__ alpha,
    const float* __restrict__ sph, const int* __restrict__ seg,
    const int* __restrict__ idx_j, const float* __restrict__ mask,
    const unsigned short* __restrict__ Bth, const unsigned short* __restrict__ Btl,
    const float* __restrict__ bias, float* __restrict__ C)
{
    __shared__ float red_s[2][15][132];
    __shared__ unsigned int ap_s[2][16][132];

    int tid = threadIdx.x;
    int sub = tid >> 8;          // atom sub-block 0/1
    int t   = tid & 127;         // feature
    int grp = (tid >> 7) & 1;    // pair-parity group
    int a = blockIdx.x * 2 + sub;
    int h = t >> 5;
    int lo = seg[a], hi = seg[a + 1];

    float acc[15];
    #pragma unroll
    for (int m = 0; m < 15; ++m) acc[m] = 0.f;

    int p = lo + grp;
    float x_cur = 0.f;
    if (p < hi) x_cur = xh[idx_j[p] * 128 + t];
    for (; p < hi; p += 2) {
        int pn = p + 2;
        float x_nxt = 0.f;
        if (pn < hi) x_nxt = xh[idx_j[pn] * 128 + t];
        float xj = x_cur * mask[p];
        float a0v = alpha[p * 12 + h];
        float a1v = alpha[p * 12 + 4 + h];
        float a2v = alpha[p * 12 + 8 + h];
        const float* sp = sph + p * 15;
        #pragma unroll
        for (int m = 0; m < 15; ++m) {
            float al = (m < 3) ? a0v : ((m < 8) ? a1v : a2v);
            acc[m] = fmaf(sp[m] * al, xj, acc[m]);
        }
        x_cur = x_nxt;
    }

    if (grp == 1) {
        #pragma unroll
        for (int m = 0; m < 15; ++m) red_s[sub][m][t] = acc[m];
    }
    __syncthreads();
    if (grp == 0) {
        #pragma unroll
        for (int m = 0; m < 15; ++m) {
            float v = acc[m] + red_s[sub][m][t];
            unsigned short hh = bf16_rne(v);
            unsigned short ll = bf16_rne(v - bf16_tof(hh));
            ap_s[sub][m][t] = ((unsigned int)hh << 16) | (unsigned int)ll;
        }
        ap_s[sub][15][t] = 0u;   // zero pad row
    }
    __syncthreads();

    // Phase 2: per-atom 16(rows,15 used) x 128(cols) x 128(k) GEMM.
    // Waves 0-3 -> atom 0, waves 4-7 -> atom 1; each wave owns 32 cols.
    int wave = tid >> 6, lane = tid & 63;
    int quad = lane >> 4, l15 = lane & 15;
    int am = wave >> 2;
    int cb = (wave & 3) * 32;
    long ga = (long)blockIdx.x * 2 + am;

    short8 ah[4], al[4];
    #pragma unroll
    for (int ks = 0; ks < 4; ++ks) {
        const unsigned int* hp = &ap_s[am][l15][ks * 32 + quad * 8];
        uint4 u01 = *(const uint4*)hp;
        uint4 u23 = *(const uint4*)(hp + 4);
        unsigned int u[8] = {u01.x, u01.y, u01.z, u01.w, u23.x, u23.y, u23.z, u23.w};
        frag_cast fh, fl;
        #pragma unroll
        for (int q = 0; q < 4; ++q) {
            unsigned int a0 = u[2 * q], a1 = u[2 * q + 1];
            fh.i[q] = (int)((a0 >> 16) | (a1 & 0xffff0000u));
            fl.i[q] = (int)((a0 & 0xffffu) | (a1 << 16));
        }
        ah[ks] = fh.s;
        al[ks] = fl.s;
    }

    #pragma unroll
    for (int ct = 0; ct < 2; ++ct) {
        int c = cb + ct * 16;
        short8 bh[4], bl[4];
        #pragma unroll
        for (int ks = 0; ks < 4; ++ks) {
            int off = (c + l15) * 128 + ks * 32 + quad * 8;
            bh[ks] = *(const short8*)(Bth + off);
            bl[ks] = *(const short8*)(Btl + off);
        }
        f32x4 oacc = {0.f, 0.f, 0.f, 0.f};
        #pragma unroll
        for (int ks = 0; ks < 4; ++ks) {
            oacc = __builtin_amdgcn_mfma_f32_16x16x32_bf16(ah[ks], bh[ks], oacc, 0, 0, 0);
            oacc = __builtin_amdgcn_mfma_f32_16x16x32_bf16(al[ks], bh[ks], oacc, 0, 0, 0);
            oacc = __builtin_amdgcn_mfma_f32_16x16x32_bf16(ah[ks], bl[ks], oacc, 0, 0, 0);
        }
        float bv = bias[c + l15];
        #pragma unroll
        for (int r = 0; r < 4; ++r) {
            int row = quad * 4 + r;
            if (row < 15)
                C[(ga * 15 + row) * 128 + c + l15] = oacc[r] + bv;
        }
    }
}

extern "C" void kernel_launch(void* const* d_in, const int* in_sizes, int n_in,
                              void* d_out, int out_size, void* d_ws, size_t ws_size,
                              hipStream_t stream) {
    const float* x        = (const float*)d_in[0];
    const float* rbf_ij   = (const float*)d_in[1];
    const float* sph_ij   = (const float*)d_in[2];
    const float* phi_r    = (const float*)d_in[3];
    const int*   idx_i    = (const int*)d_in[4];
    const int*   idx_j    = (const int*)d_in[5];
    const float* pmask    = (const float*)d_in[6];
    const float* W_Q      = (const float*)d_in[7];
    const float* W_K      = (const float*)d_in[8];
    const float* W_in     = (const float*)d_in[9];
    const float* b_in     = (const float*)d_in[10];
    const float* W_f1     = (const float*)d_in[11];
    const float* b_f1     = (const float*)d_in[12];
    const float* W_f2     = (const float*)d_in[13];
    const float* b_f2     = (const float*)d_in[14];
    const float* W_out    = (const float*)d_in[15];
    const float* b_out    = (const float*)d_in[16];
    float* out = (float*)d_out;

    float* ws    = (float*)d_ws;
    float* xh    = ws;                                   // 10000*128
    float* Qbuf  = xh + N_ATOMS * F_DIM;                 // 10000*384
    float* Kbuf  = Qbuf + N_ATOMS * 384;                 // 10000*384
    float* alpha = Kbuf + N_ATOMS * 384;                 // 100000*12
    int*   seg   = (int*)(alpha + N_PAIR * 12);          // 10001 ints
    unsigned short* Bth = (unsigned short*)(seg + 10432); // 16384 bf16
    unsigned short* Btl = Bth + 16384;                    // 16384 bf16
    unsigned short* W2h = Btl + 16384;                    // 12288 bf16 (W_f2^T hi)
    unsigned short* W2l = W2h + 12288;                    // 12288 bf16 (W_f2^T lo)

    k_seg<<<(N_ATOMS + 256) / 256, 256, 0, stream>>>(idx_i, seg);
    k_cvt_b<<<64, 256, 0, stream>>>(W_out, Bth, Btl);
    k_cvt_w2<<<48, 256, 0, stream>>>(W_f2, W2h, W2l);
    k_gemm128<<<(N_ATOMS + 127) / 128, 256, 0, stream>>>(x, W_in, b_in, xh, N_ATOMS);
    k_qk<<<(N_ATOMS + 31) / 32, 384, 0, stream>>>(xh, W_Q, W_K, Qbuf, Kbuf);
    k_pair<<<N_PAIR / 16, 256, 0, stream>>>(rbf_ij, phi_r, pmask, idx_i, idx_j,
                                            W_f1, b_f1, W2h, W2l, b_f2,
                                            Qbuf, Kbuf, alpha);
    k_agg_out<<<N_ATOMS / 2, 512, 0, stream>>>(xh, alpha, sph_ij, seg, idx_j, pmask,
                                               Bth, Btl, b_out, out);
}

// Round 3
// 365.794 us; speedup vs baseline: 1.0703x; 1.0703x over previous
//
#include <hip/hip_runtime.h>
#include <hip/hip_bf16.h>

#define N_ATOMS 10000
#define N_PAIR  100000
#define F_DIM   128
#define N_HEAD  4
#define FH      32
#define N_DEG   3
#define M_TOT   15
#define K_RBF   32

typedef __attribute__((ext_vector_type(8))) short short8;   // 8 bf16 = 4 VGPRs
typedef __attribute__((ext_vector_type(4))) float f32x4;

union frag_cast { int i[4]; short8 s; };

__device__ __forceinline__ float sspf(float v) {
    float sp = fmaxf(v, 0.f) + log1pf(expf(-fabsf(v)));
    return sp - 0.69314718055994531f;
}

__device__ __forceinline__ unsigned short bf16_rne(float x) {
    unsigned int u = __float_as_uint(x);
    unsigned int r = u + 0x7fffu + ((u >> 16) & 1u);
    return (unsigned short)(r >> 16);
}
__device__ __forceinline__ float bf16_tof(unsigned short h) {
    return __uint_as_float(((unsigned int)h) << 16);
}

// ---------------- Generic 128-col GEMM (fp32, used for x@W_in only) ---------
__global__ __launch_bounds__(256) void k_gemm128(
    const float* __restrict__ A, const float* __restrict__ B,
    const float* __restrict__ bias, float* __restrict__ C, int rows)
{
    __shared__ float As[32][132];
    __shared__ float Bs[32][132];
    int r0 = blockIdx.x * 128;
    int t = threadIdx.x;
    int ty = t >> 4, tx = t & 15;

    float acc[8][8];
    #pragma unroll
    for (int i = 0; i < 8; ++i)
        #pragma unroll
        for (int j = 0; j < 8; ++j) acc[i][j] = 0.f;

    for (int k0 = 0; k0 < 128; k0 += 32) {
        #pragma unroll
        for (int r = 0; r < 16; ++r) {
            int idx = t + 256 * r;
            int row = idx >> 5, kk = idx & 31;
            int grow = r0 + row;
            As[kk][row] = (grow < rows) ? A[grow * 128 + k0 + kk] : 0.f;
        }
        #pragma unroll
        for (int r = 0; r < 16; ++r) {
            int idx = t + 256 * r;
            int kk = idx >> 7, c = idx & 127;
            Bs[kk][c] = B[(k0 + kk) * 128 + c];
        }
        __syncthreads();

        #pragma unroll
        for (int kk = 0; kk < 32; ++kk) {
            float a[8], b[8];
            *(float4*)&a[0] = *(const float4*)&As[kk][ty * 4];
            *(float4*)&a[4] = *(const float4*)&As[kk][64 + ty * 4];
            *(float4*)&b[0] = *(const float4*)&Bs[kk][tx * 4];
            *(float4*)&b[4] = *(const float4*)&Bs[kk][64 + tx * 4];
            #pragma unroll
            for (int i = 0; i < 8; ++i)
                #pragma unroll
                for (int j = 0; j < 8; ++j)
                    acc[i][j] = fmaf(a[i], b[j], acc[i][j]);
        }
        __syncthreads();
    }

    float bj[8];
    #pragma unroll
    for (int j = 0; j < 4; ++j) { bj[j] = bias[tx * 4 + j]; bj[4 + j] = bias[64 + tx * 4 + j]; }

    #pragma unroll
    for (int i = 0; i < 8; ++i) {
        int row = r0 + ((i < 4) ? (ty * 4 + i) : (64 + ty * 4 + (i - 4)));
        if (row < rows) {
            float4 v0, v1;
            v0.x = acc[i][0] + bj[0]; v0.y = acc[i][1] + bj[1];
            v0.z = acc[i][2] + bj[2]; v0.w = acc[i][3] + bj[3];
            v1.x = acc[i][4] + bj[4]; v1.y = acc[i][5] + bj[5];
            v1.z = acc[i][6] + bj[6]; v1.w = acc[i][7] + bj[7];
            *(float4*)&C[row * 128 + tx * 4] = v0;
            *(float4*)&C[row * 128 + 64 + tx * 4] = v1;
        }
    }
}

// ---------------- Q/K projection: 32 atoms/block (313 blocks) ---------------
__global__ __launch_bounds__(384) void k_qk(
    const float* __restrict__ xh, const float* __restrict__ W_Q,
    const float* __restrict__ W_K, float* __restrict__ Q, float* __restrict__ K)
{
    __shared__ float xfs[32][128];
    int t = threadIdx.x;                 // == e
    int h = (t >> 5) & 3;
    float wq[32], wk[32];
    const float4* wqp = (const float4*)(W_Q + t * 32);
    const float4* wkp = (const float4*)(W_K + t * 32);
    #pragma unroll
    for (int j4 = 0; j4 < 8; ++j4) {
        float4 a = wqp[j4], b = wkp[j4];
        wq[4 * j4 + 0] = a.x; wq[4 * j4 + 1] = a.y; wq[4 * j4 + 2] = a.z; wq[4 * j4 + 3] = a.w;
        wk[4 * j4 + 0] = b.x; wk[4 * j4 + 1] = b.y; wk[4 * j4 + 2] = b.z; wk[4 * j4 + 3] = b.w;
    }
    int ab = blockIdx.x * 32;
    for (int idx = t; idx < 4096; idx += 384) {
        int aa = idx >> 7, f = idx & 127;
        int ag = ab + aa;
        xfs[aa][f] = (ag < N_ATOMS) ? xh[ag * 128 + f] : 0.f;
    }
    __syncthreads();
    for (int aa = 0; aa < 32; ++aa) {
        int ag = ab + aa;
        if (ag >= N_ATOMS) break;
        const float4* xv = (const float4*)&xfs[aa][h * 32];
        float q0 = 0.f, q1 = 0.f, k0 = 0.f, k1 = 0.f;
        #pragma unroll
        for (int j4 = 0; j4 < 8; j4 += 2) {
            float4 x0 = xv[j4], x1 = xv[j4 + 1];
            q0 = fmaf(wq[4 * j4 + 0], x0.x, q0); q0 = fmaf(wq[4 * j4 + 1], x0.y, q0);
            q0 = fmaf(wq[4 * j4 + 2], x0.z, q0); q0 = fmaf(wq[4 * j4 + 3], x0.w, q0);
            q1 = fmaf(wq[4 * j4 + 4], x1.x, q1); q1 = fmaf(wq[4 * j4 + 5], x1.y, q1);
            q1 = fmaf(wq[4 * j4 + 6], x1.z, q1); q1 = fmaf(wq[4 * j4 + 7], x1.w, q1);
            k0 = fmaf(wk[4 * j4 + 0], x0.x, k0); k0 = fmaf(wk[4 * j4 + 1], x0.y, k0);
            k0 = fmaf(wk[4 * j4 + 2], x0.z, k0); k0 = fmaf(wk[4 * j4 + 3], x0.w, k0);
            k1 = fmaf(wk[4 * j4 + 4], x1.x, k1); k1 = fmaf(wk[4 * j4 + 5], x1.y, k1);
            k1 = fmaf(wk[4 * j4 + 6], x1.z, k1); k1 = fmaf(wk[4 * j4 + 7], x1.w, k1);
        }
        Q[ag * 384 + t] = q0 + q1;
        K[ag * 384 + t] = k0 + k1;
    }
}

// ---------------- W_f2 -> transposed hi/lo bf16  [e][k] ---------------------
__global__ __launch_bounds__(256) void k_cvt_w2(
    const float* __restrict__ W, unsigned short* __restrict__ Wh,
    unsigned short* __restrict__ Wl)
{
    int idx = blockIdx.x * 256 + threadIdx.x;   // 12288 total
    if (idx < 12288) {
        int e = idx >> 5, k = idx & 31;
        float v = W[k * 384 + e];               // W_f2 is [32][384]
        unsigned short h = bf16_rne(v);
        unsigned short l = bf16_rne(v - bf16_tof(h));
        Wh[e * 32 + k] = h;
        Wl[e * 32 + k] = l;
    }
}

// ---------------- Pair kernel: MFMA for h1 @ W_f2 ---------------------------
// 16 pairs/block, 256 threads (4 waves), grid 6250. LDS ~27.5 KB -> 5
// blocks/CU (20 waves). g_s padded to 388 floats/row: row-stride = 16 mod 32
// banks -> quad reads are 2-way conflicted (free). bf16 hi/lo MFMA keeps
// fp32-class precision.
__global__ __launch_bounds__(256) void k_pair(
    const float* __restrict__ rbf, const float* __restrict__ phi,
    const float* __restrict__ mask, const int* __restrict__ idx_i,
    const int* __restrict__ idx_j, const float* __restrict__ W_f1,
    const float* __restrict__ b_f1, const unsigned short* __restrict__ W2h,
    const unsigned short* __restrict__ W2l, const float* __restrict__ b_f2,
    const float* __restrict__ Q, const float* __restrict__ K,
    float* __restrict__ alpha)
{
    __shared__ float g_s[16][388];            // 24.8 KB; also staging for rbf/W_f1
    __shared__ unsigned int h1p_s[16][36];    // packed (hi<<16)|lo bf16, padded
    __shared__ int   i_s[16];
    __shared__ int   j_s[16];
    __shared__ float phim_s[16];              // phi * m^2 * 1/sqrt(32)

    float (*rbf_s)[33] = (float (*)[33])(&g_s[0][0]);           // 16 rows
    float (*wf1_s)[33] = (float (*)[33])(&g_s[0][0] + 16 * 33); // 32 rows

    int t = threadIdx.x;
    int p0 = blockIdx.x * 16;                 // N_PAIR = 6250*16 exactly

    // stage rbf (16x32) and W_f1 (32x32) into the (to-be-overwritten) g region
    for (int idx = t; idx < 1536; idx += 256) {
        if (idx < 512) {
            rbf_s[idx >> 5][idx & 31] = rbf[p0 * 32 + idx];
        } else {
            int k = idx - 512;
            wf1_s[k >> 5][k & 31] = W_f1[k];
        }
    }
    if (t < 16) {
        int pg = p0 + t;
        i_s[t] = idx_i[pg];
        j_s[t] = idx_j[pg];
        float m = mask[pg];
        phim_s[t] = phi[pg] * m * m * 0.17677669529663687f;
    }
    __syncthreads();

    // h1 = ssp(rbf @ W_f1 + b1), split to bf16 hi/lo, pack into LDS
    {
        int p = t >> 4, c0 = (t & 15) * 2;
        float acc0 = b_f1[c0], acc1 = b_f1[c0 + 1];
        #pragma unroll
        for (int k = 0; k < 32; ++k) {
            float rv = rbf_s[p][k];
            acc0 = fmaf(rv, wf1_s[k][c0], acc0);
            acc1 = fmaf(rv, wf1_s[k][c0 + 1], acc1);
        }
        float h0 = sspf(acc0), h1v = sspf(acc1);
        unsigned short hh0 = bf16_rne(h0);
        unsigned short ll0 = bf16_rne(h0 - bf16_tof(hh0));
        unsigned short hh1 = bf16_rne(h1v);
        unsigned short ll1 = bf16_rne(h1v - bf16_tof(hh1));
        h1p_s[p][c0]     = ((unsigned int)hh0 << 16) | (unsigned int)ll0;
        h1p_s[p][c0 + 1] = ((unsigned int)hh1 << 16) | (unsigned int)ll1;
    }
    __syncthreads();   // h1 done; now safe to overwrite rbf/W_f1 staging with g

    // g[p][e] = Q[i_p*384+e] * K[j_p*384+e] via coalesced float4 loads
    #pragma unroll
    for (int it = 0; it < 6; ++it) {
        int idx = it * 256 + t;               // 0..1535 = 16 pairs x 96 float4
        int p = idx / 96;
        int c4 = idx - p * 96;
        const float4* qp = (const float4*)(Q + i_s[p] * 384) + c4;
        const float4* kp = (const float4*)(K + j_s[p] * 384) + c4;
        float4 qv = *qp, kv = *kp;
        float4 gv;
        gv.x = qv.x * kv.x; gv.y = qv.y * kv.y;
        gv.z = qv.z * kv.z; gv.w = qv.w * kv.w;
        *(float4*)&g_s[p][c4 * 4] = gv;
    }
    __syncthreads();

    // MFMA phase: S = h1 @ W_f2 (K=32 = one mfma k-step), then
    // alpha[p][dh] = phim * sum_e (S[p][e] + b2[e]) * g[p][e]
    int wave = t >> 6, lane = t & 63;
    int quad = lane >> 4, l15 = lane & 15;

    // A fragments (single 16-row tile), hi and lo
    short8 ah, al;
    {
        const unsigned int* hp = &h1p_s[l15][quad * 8];
        uint4 u01 = *(const uint4*)hp;
        uint4 u23 = *(const uint4*)(hp + 4);
        unsigned int u[8] = {u01.x, u01.y, u01.z, u01.w, u23.x, u23.y, u23.z, u23.w};
        frag_cast fh, fl;
        #pragma unroll
        for (int q = 0; q < 4; ++q) {
            unsigned int a0 = u[2 * q], a1 = u[2 * q + 1];
            fh.i[q] = (int)((a0 >> 16) | (a1 & 0xffff0000u));
            fl.i[q] = (int)((a0 & 0xffffu) | (a1 << 16));
        }
        ah = fh.s;
        al = fl.s;
    }

    #pragma unroll
    for (int dd = 0; dd < 3; ++dd) {
        int dh = wave * 3 + dd;
        int e_base = dh * 32;
        // B fragments for the dh group's two 16-col tiles
        short8 bh0 = *(const short8*)(W2h + (e_base + l15) * 32 + quad * 8);
        short8 bl0 = *(const short8*)(W2l + (e_base + l15) * 32 + quad * 8);
        short8 bh1 = *(const short8*)(W2h + (e_base + 16 + l15) * 32 + quad * 8);
        short8 bl1 = *(const short8*)(W2l + (e_base + 16 + l15) * 32 + quad * 8);
        float b2v0 = b_f2[e_base + l15];
        float b2v1 = b_f2[e_base + 16 + l15];

        f32x4 s0 = {0.f, 0.f, 0.f, 0.f};
        f32x4 s1 = {0.f, 0.f, 0.f, 0.f};
        s0 = __builtin_amdgcn_mfma_f32_16x16x32_bf16(ah, bh0, s0, 0, 0, 0);
        s1 = __builtin_amdgcn_mfma_f32_16x16x32_bf16(ah, bh1, s1, 0, 0, 0);
        s0 = __builtin_amdgcn_mfma_f32_16x16x32_bf16(al, bh0, s0, 0, 0, 0);
        s1 = __builtin_amdgcn_mfma_f32_16x16x32_bf16(al, bh1, s1, 0, 0, 0);
        s0 = __builtin_amdgcn_mfma_f32_16x16x32_bf16(ah, bl0, s0, 0, 0, 0);
        s1 = __builtin_amdgcn_mfma_f32_16x16x32_bf16(ah, bl1, s1, 0, 0, 0);

        float vsum[4];
        #pragma unroll
        for (int r = 0; r < 4; ++r) {
            int prow = quad * 4 + r;
            float v = (s0[r] + b2v0) * g_s[prow][e_base + l15]
                    + (s1[r] + b2v1) * g_s[prow][e_base + 16 + l15];
            #pragma unroll
            for (int off = 8; off >= 1; off >>= 1)
                v += __shfl_xor(v, off, 16);
            vsum[r] = v;
        }
        if (l15 == 0) {
            #pragma unroll
            for (int r = 0; r < 4; ++r) {
                int prow = quad * 4 + r;
                alpha[(p0 + prow) * 12 + dh] = vsum[r] * phim_s[prow];
            }
        }
    }
}

__device__ __forceinline__ int lower_bound_i(const int* __restrict__ arr, int n, int val) {
    int lo = 0, hi = n;
    while (lo < hi) {
        int mid = (lo + hi) >> 1;
        if (arr[mid] < val) lo = mid + 1; else hi = mid;
    }
    return lo;
}

__global__ __launch_bounds__(256) void k_seg(const int* __restrict__ idx_i,
                                             int* __restrict__ seg)
{
    int a = blockIdx.x * 256 + threadIdx.x;
    if (a <= N_ATOMS) seg[a] = lower_bound_i(idx_i, N_PAIR, a);
}

// ---------------- W_out -> transposed hi/lo bf16 ----------------------------
__global__ __launch_bounds__(256) void k_cvt_b(
    const float* __restrict__ W, unsigned short* __restrict__ Bth,
    unsigned short* __restrict__ Btl)
{
    int idx = blockIdx.x * 256 + threadIdx.x;   // 16384 total
    int cc = idx >> 7, kk = idx & 127;
    float v = W[kk * 128 + cc];                 // transpose read
    unsigned short h = bf16_rne(v);
    unsigned short l = bf16_rne(v - bf16_tof(h));
    Bth[cc * 128 + kk] = h;
    Btl[cc * 128 + kk] = l;
}

// ---------------- Fused segment aggregation + out GEMM ----------------------
// 1 atom/block, 512 threads = 4 pair-parallel groups of 128 (f-dim).
// Phase 1: segment reduction with depth-1 software pipeline on ALL streams
// (sph/alpha/mask/xh) and idx_j prefetched one step further ahead, so no
// iteration has a load-use stall. Phase 2: 16x128x128 bf16x3 MFMA per atom
// from LDS, 8 waves = 8 col-tiles.
__global__ __launch_bounds__(512) void k_agg_out(
    const float* __restrict__ xh, const float* __restrict__ alpha,
    const float* __restrict__ sph, const int* __restrict__ seg,
    const int* __restrict__ idx_j, const float* __restrict__ mask,
    const unsigned short* __restrict__ Bth, const unsigned short* __restrict__ Btl,
    const float* __restrict__ bias, float* __restrict__ C)
{
    __shared__ float red_s[3][15][132];
    __shared__ unsigned int ap_s[16][132];

    int tid = threadIdx.x;
    int t   = tid & 127;         // feature
    int grp = tid >> 7;          // pair group 0..3
    int a = blockIdx.x;
    int h = t >> 5;
    int lo = seg[a], hi = seg[a + 1];

    float acc[15];
    #pragma unroll
    for (int m = 0; m < 15; ++m) acc[m] = 0.f;

    // ---- software-pipelined segment loop (stride 4) ----
    int p = lo + grp;
    float x_c = 0.f, m_c = 0.f, a_c0 = 0.f, a_c1 = 0.f, a_c2 = 0.f;
    float s_c[15];
    int jn = 0;                  // idx_j for p+4
    if (p < hi) {
        int j0 = idx_j[p];
        m_c  = mask[p];
        a_c0 = alpha[p * 12 + h];
        a_c1 = alpha[p * 12 + 4 + h];
        a_c2 = alpha[p * 12 + 8 + h];
        #pragma unroll
        for (int m = 0; m < 15; ++m) s_c[m] = sph[p * 15 + m];
        x_c = xh[j0 * 128 + t];
        if (p + 4 < hi) jn = idx_j[p + 4];
    }

    while (p < hi) {
        int pn = p + 4;
        float x_n = 0.f, m_n = 0.f, an0 = 0.f, an1 = 0.f, an2 = 0.f;
        float s_n[15];
        #pragma unroll
        for (int m = 0; m < 15; ++m) s_n[m] = 0.f;
        int jn2 = 0;
        if (pn < hi) {
            x_n = xh[jn * 128 + t];              // jn prefetched last iter
            m_n = mask[pn];
            an0 = alpha[pn * 12 + h];
            an1 = alpha[pn * 12 + 4 + h];
            an2 = alpha[pn * 12 + 8 + h];
            #pragma unroll
            for (int m = 0; m < 15; ++m) s_n[m] = sph[pn * 15 + m];
            if (pn + 4 < hi) jn2 = idx_j[pn + 4];
        }
        // compute with current (already in registers -> no stall)
        float xj = x_c * m_c;
        #pragma unroll
        for (int m = 0; m < 15; ++m) {
            float av = (m < 3) ? a_c0 : ((m < 8) ? a_c1 : a_c2);
            acc[m] = fmaf(s_c[m] * av, xj, acc[m]);
        }
        // rotate pipeline
        x_c = x_n; m_c = m_n; a_c0 = an0; a_c1 = an1; a_c2 = an2;
        #pragma unroll
        for (int m = 0; m < 15; ++m) s_c[m] = s_n[m];
        jn = jn2;
        p = pn;
    }

    if (grp >= 1) {
        #pragma unroll
        for (int m = 0; m < 15; ++m) red_s[grp - 1][m][t] = acc[m];
    }
    __syncthreads();
    if (grp == 0) {
        #pragma unroll
        for (int m = 0; m < 15; ++m) {
            float v = acc[m] + red_s[0][m][t] + red_s[1][m][t] + red_s[2][m][t];
            unsigned short hh = bf16_rne(v);
            unsigned short ll = bf16_rne(v - bf16_tof(hh));
            ap_s[m][t] = ((unsigned int)hh << 16) | (unsigned int)ll;
        }
        ap_s[15][t] = 0u;   // zero pad row
    }
    __syncthreads();

    // ---- Phase 2: 16(rows,15 used) x 128(cols) x 128(k) GEMM, 8 waves ----
    int wave = tid >> 6, lane = tid & 63;
    int quad = lane >> 4, l15 = lane & 15;
    int c = wave * 16;           // each wave owns one 16-col tile

    short8 fa_h[4], fa_l[4];
    #pragma unroll
    for (int ks = 0; ks < 4; ++ks) {
        const unsigned int* hp = &ap_s[l15][ks * 32 + quad * 8];
        uint4 u01 = *(const uint4*)hp;
        uint4 u23 = *(const uint4*)(hp + 4);
        unsigned int u[8] = {u01.x, u01.y, u01.z, u01.w, u23.x, u23.y, u23.z, u23.w};
        frag_cast fh, fl;
        #pragma unroll
        for (int q = 0; q < 4; ++q) {
            unsigned int a0 = u[2 * q], a1 = u[2 * q + 1];
            fh.i[q] = (int)((a0 >> 16) | (a1 & 0xffff0000u));
            fl.i[q] = (int)((a0 & 0xffffu) | (a1 << 16));
        }
        fa_h[ks] = fh.s;
        fa_l[ks] = fl.s;
    }

    short8 bh[4], bl[4];
    #pragma unroll
    for (int ks = 0; ks < 4; ++ks) {
        int off = (c + l15) * 128 + ks * 32 + quad * 8;
        bh[ks] = *(const short8*)(Bth + off);
        bl[ks] = *(const short8*)(Btl + off);
    }
    f32x4 oacc = {0.f, 0.f, 0.f, 0.f};
    #pragma unroll
    for (int ks = 0; ks < 4; ++ks) {
        oacc = __builtin_amdgcn_mfma_f32_16x16x32_bf16(fa_h[ks], bh[ks], oacc, 0, 0, 0);
        oacc = __builtin_amdgcn_mfma_f32_16x16x32_bf16(fa_l[ks], bh[ks], oacc, 0, 0, 0);
        oacc = __builtin_amdgcn_mfma_f32_16x16x32_bf16(fa_h[ks], bl[ks], oacc, 0, 0, 0);
    }
    float bv = bias[c + l15];
    #pragma unroll
    for (int r = 0; r < 4; ++r) {
        int row = quad * 4 + r;
        if (row < 15)
            C[((long)a * 15 + row) * 128 + c + l15] = oacc[r] + bv;
    }
}

extern "C" void kernel_launch(void* const* d_in, const int* in_sizes, int n_in,
                              void* d_out, int out_size, void* d_ws, size_t ws_size,
                              hipStream_t stream) {
    const float* x        = (const float*)d_in[0];
    const float* rbf_ij   = (const float*)d_in[1];
    const float* sph_ij   = (const float*)d_in[2];
    const float* phi_r    = (const float*)d_in[3];
    const int*   idx_i    = (const int*)d_in[4];
    const int*   idx_j    = (const int*)d_in[5];
    const float* pmask    = (const float*)d_in[6];
    const float* W_Q      = (const float*)d_in[7];
    const float* W_K      = (const float*)d_in[8];
    const float* W_in     = (const float*)d_in[9];
    const float* b_in     = (const float*)d_in[10];
    const float* W_f1     = (const float*)d_in[11];
    const float* b_f1     = (const float*)d_in[12];
    const float* W_f2     = (const float*)d_in[13];
    const float* b_f2     = (const float*)d_in[14];
    const float* W_out    = (const float*)d_in[15];
    const float* b_out    = (const float*)d_in[16];
    float* out = (float*)d_out;

    float* ws    = (float*)d_ws;
    float* xh    = ws;                                   // 10000*128
    float* Qbuf  = xh + N_ATOMS * F_DIM;                 // 10000*384
    float* Kbuf  = Qbuf + N_ATOMS * 384;                 // 10000*384
    float* alpha = Kbuf + N_ATOMS * 384;                 // 100000*12
    int*   seg   = (int*)(alpha + N_PAIR * 12);          // 10001 ints
    unsigned short* Bth = (unsigned short*)(seg + 10432); // 16384 bf16
    unsigned short* Btl = Bth + 16384;                    // 16384 bf16
    unsigned short* W2h = Btl + 16384;                    // 12288 bf16 (W_f2^T hi)
    unsigned short* W2l = W2h + 12288;                    // 12288 bf16 (W_f2^T lo)

    k_seg<<<(N_ATOMS + 256) / 256, 256, 0, stream>>>(idx_i, seg);
    k_cvt_b<<<64, 256, 0, stream>>>(W_out, Bth, Btl);
    k_cvt_w2<<<48, 256, 0, stream>>>(W_f2, W2h, W2l);
    k_gemm128<<<(N_ATOMS + 127) / 128, 256, 0, stream>>>(x, W_in, b_in, xh, N_ATOMS);
    k_qk<<<(N_ATOMS + 31) / 32, 384, 0, stream>>>(xh, W_Q, W_K, Qbuf, Kbuf);
    k_pair<<<N_PAIR / 16, 256, 0, stream>>>(rbf_ij, phi_r, pmask, idx_i, idx_j,
                                            W_f1, b_f1, W2h, W2l, b_f2,
                                            Qbuf, Kbuf, alpha);
    k_agg_out<<<N_ATOMS, 512, 0, stream>>>(xh, alpha, sph_ij, seg, idx_j, pmask,
                                           Bth, Btl, b_out, out);
}